// Round 2
// baseline (476.068 us; speedup 1.0000x reference)
//
#include <hip/hip_runtime.h>

#define T_  8192
#define E_  256
#define BS_ 128

typedef __attribute__((ext_vector_type(8))) short bf16x8;
typedef __attribute__((ext_vector_type(4))) float f32x4;
typedef __attribute__((ext_vector_type(4))) unsigned int u32x4;

// Pair-convert via native __bf16 casts: compiler emits v_cvt_pk_bf16_f32 (RTNE),
// 1 instr / 2 elements vs ~3-4 VALU ops/element for manual bit-math (m240).
__device__ __forceinline__ unsigned pkbf(float a, float b) {
    unsigned short ua = __builtin_bit_cast(unsigned short, (__bf16)a);
    unsigned short ub = __builtin_bit_cast(unsigned short, (__bf16)b);
    return (unsigned)ua | ((unsigned)ub << 16);
}

__device__ __forceinline__ unsigned short bf1(float a) {
    return __builtin_bit_cast(unsigned short, (__bf16)a);
}

__device__ __forceinline__ bf16x8 pack8(f32x4 a, f32x4 b) {
    u32x4 u;
    u[0] = pkbf(a[0], a[1]); u[1] = pkbf(a[2], a[3]);
    u[2] = pkbf(b[0], b[1]); u[3] = pkbf(b[2], b[3]);
    return __builtin_bit_cast(bf16x8, u);
}

// Raw barrier: orders LDS only (lgkmcnt(0) + s_barrier). Global loads/stores
// stay in flight across it — the whole schedule below depends on that.
__device__ __forceinline__ void lds_barrier() {
    asm volatile("s_waitcnt lgkmcnt(0)" ::: "memory");
    __builtin_amdgcn_s_barrier();
}

// Fused diag-block attention, one WG per (batch,block) tile, 512 thr = 8 waves.
// Load-front schedule: issue Q (all 8 k-steps) -> stage K (bf16, swizzled LDS)
// -> pack Q frags -> issue V ks=0,1 -> barrier. QK^T and softmax are then
// vmem-free while Q/K-retire + V prefetch latency hides under them. A is
// stored fp32 nontemporal and never read back; P bounces through LDS (reuses
// K buffer); PV reads V straight from global (each byte once per WG), tail
// k-steps prefetched at distance 2. Loads are cache-retained (no NT) to
// maximize cross-dispatch L3 reuse; stores stay NT.
__global__ __launch_bounds__(512, 4) void dba_fused(
        const float* __restrict__ Qg, const float* __restrict__ Kg,
        const float* __restrict__ Vg, float* __restrict__ Ag,
        float* __restrict__ Og)
{
    __shared__ unsigned short Sm[BS_ * E_];   // 64 KB: K[128][256] bf16; later P[128][128] bf16 in low 32 KB

    const int tid  = threadIdx.x;
    const int lane = tid & 63;
    const int w    = tid >> 6;     // wave 0..7
    const int cl   = lane & 15;    // col (C layout) / m (A layout) / n (B layout)
    const int g    = lane >> 4;    // quad group 0..3
    const int bi   = blockIdx.x >> 6;
    const int ni   = blockIdx.x & 63;
    const int base  = (bi * T_ + ni * BS_) * E_;
    const int abase = (bi * T_ + ni * BS_) * BS_;
    const int vcol  = w * 32 + cl;             // this wave's O/V column base

    // ---- 1. issue ALL Q loads (8 k-steps x 32B/lane); they retire under K staging ----
    const float* qp = Qg + base + (w * 16 + cl) * E_;
    f32x4 qf[16];
    #pragma unroll
    for (int i = 0; i < 16; ++i)
        qf[i] = *(const f32x4*)(qp + (i >> 1) * 32 + g * 8 + (i & 1) * 4);

    // ---- 2. stage K: fp32 global -> bf16 LDS, 16B-chunk XOR swizzle by (row&15) ----
    {
        const int c4   = lane * 4;            // col 0..252 step 4
        const int chnk = c4 >> 3;
        const int klow = c4 & 7;              // 0 or 4
        #pragma unroll 8
        for (int i = 0; i < 16; ++i) {
            const int n = i * 8 + w;          // key row 0..127
            f32x4 kv = *(const f32x4*)(Kg + base + n * E_ + c4);
            const int cp = chnk ^ (n & 15);
            uint2 pk;
            pk.x = pkbf(kv[0], kv[1]);
            pk.y = pkbf(kv[2], kv[3]);
            *(uint2*)&Sm[n * E_ + cp * 8 + klow] = pk;
        }
    }

    // ---- 3. pack Q fragments (Q loads have long since landed) ----
    bf16x8 aq[8];
    #pragma unroll
    for (int ks = 0; ks < 8; ++ks)
        aq[ks] = pack8(qf[2 * ks], qf[2 * ks + 1]);

    // ---- 4. issue V k-steps 0,1: latency hides under QK^T + softmax + P-write ----
    float vb[2][16];
    #pragma unroll
    for (int t = 0; t < 16; ++t)
        vb[0][t] = Vg[base + (g * 8 + (t & 7)) * E_ + vcol + (t >> 3) * 16];
    #pragma unroll
    for (int t = 0; t < 16; ++t)
        vb[1][t] = Vg[base + (32 + g * 8 + (t & 7)) * E_ + vcol + (t >> 3) * 16];

    lds_barrier();

    // ---- 5. S = Q K^T: pure LDS+MFMA, zero vmem in the loop ----
    f32x4 acc[8];
    #pragma unroll
    for (int nt = 0; nt < 8; ++nt) acc[nt] = (f32x4){0.f, 0.f, 0.f, 0.f};

    #pragma unroll
    for (int ks = 0; ks < 8; ++ks) {
        #pragma unroll
        for (int nt = 0; nt < 8; ++nt) {
            const int n  = nt * 16 + cl;      // key row
            const int cp = (ks * 4 + g) ^ cl;
            bf16x8 bk = *(const bf16x8*)&Sm[n * E_ + cp * 8];
            acc[nt] = __builtin_amdgcn_mfma_f32_16x16x32_bf16(aq[ks], bk, acc[nt], 0, 0, 0);
        }
    }

    // ---- 6. mask + softmax. C layout: col = 16*nt + cl, row = 16*w + 4*g + r ----
    const float scale = 0.0625f;               // 1/sqrt(256)
    const float L2E   = 1.4426950408889634f;
    #pragma unroll
    for (int r = 0; r < 4; ++r) {
        const int q = w * 16 + g * 4 + r;      // local query row
        float m = -__builtin_inff();
        #pragma unroll
        for (int nt = 0; nt < 8; ++nt) {
            const int c = nt * 16 + cl;
            float z = acc[nt][r] * scale;
            z = (c > q) ? -__builtin_inff() : z;
            acc[nt][r] = z;
            m = fmaxf(m, z);
        }
        m = fmaxf(m, __shfl_xor(m, 1));
        m = fmaxf(m, __shfl_xor(m, 2));
        m = fmaxf(m, __shfl_xor(m, 4));
        m = fmaxf(m, __shfl_xor(m, 8));
        float s = 0.f;
        #pragma unroll
        for (int nt = 0; nt < 8; ++nt) {
            const float p = exp2f((acc[nt][r] - m) * L2E);
            acc[nt][r] = p;
            s += p;
        }
        s += __shfl_xor(s, 1);
        s += __shfl_xor(s, 2);
        s += __shfl_xor(s, 4);
        s += __shfl_xor(s, 8);
        const float rinv = __builtin_amdgcn_rcpf(s);
        #pragma unroll
        for (int nt = 0; nt < 8; ++nt)
            acc[nt][r] *= rinv;
    }

    // ---- 7. store A (fp32, mandatory output #2). Fire-and-forget. ----
    #pragma unroll
    for (int nt = 0; nt < 8; ++nt)
        #pragma unroll
        for (int r = 0; r < 4; ++r)
            __builtin_nontemporal_store(acc[nt][r],
                Ag + abase + (w * 16 + g * 4 + r) * BS_ + nt * 16 + cl);

    lds_barrier();   // all waves done reading K-LDS; safe to overwrite with P

    // ---- 8. P (bf16) -> LDS [q][k], same 16B-chunk XOR swizzle by (q&15) ----
    #pragma unroll
    for (int nt = 0; nt < 8; ++nt)
        #pragma unroll
        for (int r = 0; r < 4; ++r) {
            const int q = w * 16 + g * 4 + r;
            const int k = nt * 16 + cl;
            Sm[q * BS_ + (((k >> 3) ^ (g * 4 + r)) * 8) + (k & 7)] = bf1(acc[nt][r]);
        }

    lds_barrier();   // P visible WG-wide

    // ---- 9. O = P V: wave w owns output cols [32w,32w+32), all 8 q-row tiles.
    //      A-operand from P-LDS (swizzled b128 reads), B-operand = V from
    //      global (each byte read exactly once per WG), depth-2 prefetch. ----
    f32x4 acc2[8][2];
    #pragma unroll
    for (int mt = 0; mt < 8; ++mt) {
        acc2[mt][0] = (f32x4){0.f, 0.f, 0.f, 0.f};
        acc2[mt][1] = (f32x4){0.f, 0.f, 0.f, 0.f};
    }

    #pragma unroll
    for (int ks = 0; ks < 4; ++ks) {
        f32x4 v0a = {vb[ks & 1][0],  vb[ks & 1][1],  vb[ks & 1][2],  vb[ks & 1][3]};
        f32x4 v0b = {vb[ks & 1][4],  vb[ks & 1][5],  vb[ks & 1][6],  vb[ks & 1][7]};
        f32x4 v1a = {vb[ks & 1][8],  vb[ks & 1][9],  vb[ks & 1][10], vb[ks & 1][11]};
        f32x4 v1b = {vb[ks & 1][12], vb[ks & 1][13], vb[ks & 1][14], vb[ks & 1][15]};
        bf16x8 bv0 = pack8(v0a, v0b);
        bf16x8 bv1 = pack8(v1a, v1b);
        if (ks < 2) {   // prefetch k-steps 2,3 into the buffer just consumed
            #pragma unroll
            for (int t = 0; t < 16; ++t)
                vb[ks & 1][t] = Vg[base + ((ks + 2) * 32 + g * 8 + (t & 7)) * E_ + vcol + (t >> 3) * 16];
        }
        #pragma unroll
        for (int mt = 0; mt < 8; ++mt) {
            const int q = mt * 16 + cl;        // P row; q&15 == cl
            const bf16x8 pa = *(const bf16x8*)&Sm[q * BS_ + (((ks * 4 + g) ^ cl) * 8)];
            acc2[mt][0] = __builtin_amdgcn_mfma_f32_16x16x32_bf16(pa, bv0, acc2[mt][0], 0, 0, 0);
            acc2[mt][1] = __builtin_amdgcn_mfma_f32_16x16x32_bf16(pa, bv1, acc2[mt][1], 0, 0, 0);
        }
    }

    #pragma unroll
    for (int mt = 0; mt < 8; ++mt)
        #pragma unroll
        for (int n2 = 0; n2 < 2; ++n2)
            #pragma unroll
            for (int r = 0; r < 4; ++r)
                __builtin_nontemporal_store(acc2[mt][n2][r],
                    Og + base + (mt * 16 + g * 4 + r) * E_ + vcol + n2 * 16);
}

extern "C" void kernel_launch(void* const* d_in, const int* in_sizes, int n_in,
                              void* d_out, int out_size, void* d_ws, size_t ws_size,
                              hipStream_t stream) {
    const float* Q = (const float*)d_in[0];
    const float* K = (const float*)d_in[1];
    const float* V = (const float*)d_in[2];
    float* O = (float*)d_out;
    const int b = in_sizes[0] / (T_ * E_);            // 16
    float* A = O + (size_t)b * T_ * E_;               // output #2 region of d_out
    dim3 grid(b * (T_ / BS_));                        // 1024 tiles
    dim3 block(512);
    dba_fused<<<grid, block, 0, stream>>>(Q, K, V, A, O);
}

// Round 3
// 473.948 us; speedup vs baseline: 1.0045x; 1.0045x over previous
//
#include <hip/hip_runtime.h>

#define T_  8192
#define E_  256
#define BS_ 128

typedef __attribute__((ext_vector_type(8))) short bf16x8;
typedef __attribute__((ext_vector_type(4))) float f32x4;
typedef __attribute__((ext_vector_type(4))) unsigned int u32x4;

// Pair-convert via native __bf16 casts: compiler emits v_cvt_pk_bf16_f32 (RTNE),
// 1 instr / 2 elements vs ~3-4 VALU ops/element for manual bit-math.
__device__ __forceinline__ unsigned pkbf(float a, float b) {
    unsigned short ua = __builtin_bit_cast(unsigned short, (__bf16)a);
    unsigned short ub = __builtin_bit_cast(unsigned short, (__bf16)b);
    return (unsigned)ua | ((unsigned)ub << 16);
}

__device__ __forceinline__ unsigned short bf1(float a) {
    return __builtin_bit_cast(unsigned short, (__bf16)a);
}

__device__ __forceinline__ bf16x8 pack8(f32x4 a, f32x4 b) {
    u32x4 u;
    u[0] = pkbf(a[0], a[1]); u[1] = pkbf(a[2], a[3]);
    u[2] = pkbf(b[0], b[1]); u[3] = pkbf(b[2], b[3]);
    return __builtin_bit_cast(bf16x8, u);
}

// Raw barrier: orders LDS only (lgkmcnt(0) + s_barrier). Global loads/stores
// stay in flight across it.
__device__ __forceinline__ void lds_barrier() {
    asm volatile("s_waitcnt lgkmcnt(0)" ::: "memory");
    __builtin_amdgcn_s_barrier();
}

// Fused diag-block attention, one WG per (batch,block) tile, 512 thr = 8 waves.
// Round-1 structure (rolling Q prefetch depth-1, V depth-2 prefetch issued
// right after QK^T, P bounced through LDS, A fp32 fire-and-forget stores,
// raw lgkm-only barriers) + native cvt_pk bf16 conversions + cache-retained
// loads + s_setprio(1) around the MFMA phases (T5: two WGs/CU run
// phase-shifted, so the CU scheduler has staging-waves vs MFMA-waves to
// arbitrate).
// NOTE round-2 lesson: do NOT preload all 8 Q k-steps — qf[16] (64 VGPR)
// blows the 128-VGPR budget and spills (+18 MB scratch writes, +55% time).
__global__ __launch_bounds__(512, 4) void dba_fused(
        const float* __restrict__ Qg, const float* __restrict__ Kg,
        const float* __restrict__ Vg, float* __restrict__ Ag,
        float* __restrict__ Og)
{
    __shared__ unsigned short Sm[BS_ * E_];   // 64 KB: K[128][256] bf16; later P[128][128] bf16 in low 32 KB

    const int tid  = threadIdx.x;
    const int lane = tid & 63;
    const int w    = tid >> 6;     // wave 0..7
    const int cl   = lane & 15;    // col (C layout) / m (A layout) / n (B layout)
    const int g    = lane >> 4;    // quad group 0..3
    const int bi   = blockIdx.x >> 6;
    const int ni   = blockIdx.x & 63;
    const int base  = (bi * T_ + ni * BS_) * E_;
    const int abase = (bi * T_ + ni * BS_) * BS_;
    const int vcol  = w * 32 + cl;             // this wave's O/V column base

    // Q fragment for ks=0, issued before K staging (raw barrier won't drain it)
    const float* qp = Qg + base + (w * 16 + cl) * E_;
    f32x4 q0 = *(const f32x4*)(qp + g * 8);
    f32x4 q1 = *(const f32x4*)(qp + g * 8 + 4);

    // ---- stage K: fp32 global -> bf16 LDS, 16B-chunk XOR swizzle by (row&15) ----
    {
        const int c4   = lane * 4;            // col 0..252 step 4
        const int chnk = c4 >> 3;
        const int klow = c4 & 7;              // 0 or 4
        #pragma unroll 8
        for (int i = 0; i < 16; ++i) {
            const int n = i * 8 + w;          // key row 0..127
            f32x4 kv = *(const f32x4*)(Kg + base + n * E_ + c4);
            const int cp = chnk ^ (n & 15);
            uint2 pk;
            pk.x = pkbf(kv[0], kv[1]);
            pk.y = pkbf(kv[2], kv[3]);
            *(uint2*)&Sm[n * E_ + cp * 8 + klow] = pk;
        }
    }
    lds_barrier();

    // ---- S = Q K^T via mfma_f32_16x16x32_bf16; wave w: 1 row-tile x 8 col-tiles ----
    f32x4 acc[8];
    #pragma unroll
    for (int nt = 0; nt < 8; ++nt) acc[nt] = (f32x4){0.f, 0.f, 0.f, 0.f};

    __builtin_amdgcn_s_setprio(1);
    for (int ks = 0; ks < 8; ++ks) {          // contraction: 8 steps of 32
        bf16x8 aq = pack8(q0, q1);
        if (ks < 7) {
            const int kn = (ks + 1) * 32 + g * 8;
            q0 = *(const f32x4*)(qp + kn);
            q1 = *(const f32x4*)(qp + kn + 4);
        }
        #pragma unroll
        for (int nt = 0; nt < 8; ++nt) {
            const int n  = nt * 16 + cl;      // key row
            const int cp = (ks * 4 + g) ^ cl;
            bf16x8 bk = *(const bf16x8*)&Sm[n * E_ + cp * 8];
            acc[nt] = __builtin_amdgcn_mfma_f32_16x16x32_bf16(aq, bk, acc[nt], 0, 0, 0);
        }
    }
    __builtin_amdgcn_s_setprio(0);

    // ---- prefetch V k-steps 0,1 (32 coalesced dwords): HBM latency hides under
    //      softmax + A-store + P-LDS write + two barriers ----
    float vb[2][16];
    #pragma unroll
    for (int t = 0; t < 16; ++t)
        vb[0][t] = Vg[base + (g * 8 + (t & 7)) * E_ + vcol + (t >> 3) * 16];
    #pragma unroll
    for (int t = 0; t < 16; ++t)
        vb[1][t] = Vg[base + (32 + g * 8 + (t & 7)) * E_ + vcol + (t >> 3) * 16];

    // ---- mask + softmax. C layout: col = 16*nt + cl, row = 16*w + 4*g + r ----
    const float scale = 0.0625f;               // 1/sqrt(256)
    const float L2E   = 1.4426950408889634f;
    #pragma unroll
    for (int r = 0; r < 4; ++r) {
        const int q = w * 16 + g * 4 + r;      // local query row
        float m = -__builtin_inff();
        #pragma unroll
        for (int nt = 0; nt < 8; ++nt) {
            const int c = nt * 16 + cl;
            float z = acc[nt][r] * scale;
            z = (c > q) ? -__builtin_inff() : z;
            acc[nt][r] = z;
            m = fmaxf(m, z);
        }
        m = fmaxf(m, __shfl_xor(m, 1));
        m = fmaxf(m, __shfl_xor(m, 2));
        m = fmaxf(m, __shfl_xor(m, 4));
        m = fmaxf(m, __shfl_xor(m, 8));
        float s = 0.f;
        #pragma unroll
        for (int nt = 0; nt < 8; ++nt) {
            const float p = exp2f((acc[nt][r] - m) * L2E);
            acc[nt][r] = p;
            s += p;
        }
        s += __shfl_xor(s, 1);
        s += __shfl_xor(s, 2);
        s += __shfl_xor(s, 4);
        s += __shfl_xor(s, 8);
        const float rinv = __builtin_amdgcn_rcpf(s);
        #pragma unroll
        for (int nt = 0; nt < 8; ++nt)
            acc[nt][r] *= rinv;
    }

    // ---- store A (fp32, mandatory output #2). Fire-and-forget. ----
    #pragma unroll
    for (int nt = 0; nt < 8; ++nt)
        #pragma unroll
        for (int r = 0; r < 4; ++r)
            __builtin_nontemporal_store(acc[nt][r],
                Ag + abase + (w * 16 + g * 4 + r) * BS_ + nt * 16 + cl);

    lds_barrier();   // all waves done reading K-LDS; safe to overwrite with P

    // ---- P (bf16) -> LDS [q][k], same 16B-chunk XOR swizzle by (q&15) ----
    #pragma unroll
    for (int nt = 0; nt < 8; ++nt)
        #pragma unroll
        for (int r = 0; r < 4; ++r) {
            const int q = w * 16 + g * 4 + r;
            const int k = nt * 16 + cl;
            Sm[q * BS_ + (((k >> 3) ^ (g * 4 + r)) * 8) + (k & 7)] = bf1(acc[nt][r]);
        }

    lds_barrier();   // P visible WG-wide

    // ---- O = P V: wave w owns output cols [32w,32w+32), all 8 q-row tiles.
    //      A-operand from P-LDS (swizzled b128 reads), B-operand = V from
    //      global (each byte read exactly once per WG), depth-2 prefetch. ----
    f32x4 acc2[8][2];
    #pragma unroll
    for (int mt = 0; mt < 8; ++mt) {
        acc2[mt][0] = (f32x4){0.f, 0.f, 0.f, 0.f};
        acc2[mt][1] = (f32x4){0.f, 0.f, 0.f, 0.f};
    }

    __builtin_amdgcn_s_setprio(1);
    #pragma unroll
    for (int ks = 0; ks < 4; ++ks) {
        f32x4 v0a = {vb[ks & 1][0],  vb[ks & 1][1],  vb[ks & 1][2],  vb[ks & 1][3]};
        f32x4 v0b = {vb[ks & 1][4],  vb[ks & 1][5],  vb[ks & 1][6],  vb[ks & 1][7]};
        f32x4 v1a = {vb[ks & 1][8],  vb[ks & 1][9],  vb[ks & 1][10], vb[ks & 1][11]};
        f32x4 v1b = {vb[ks & 1][12], vb[ks & 1][13], vb[ks & 1][14], vb[ks & 1][15]};
        bf16x8 bv0 = pack8(v0a, v0b);
        bf16x8 bv1 = pack8(v1a, v1b);
        if (ks < 2) {   // prefetch k-steps 2,3 into the buffer just consumed
            #pragma unroll
            for (int t = 0; t < 16; ++t)
                vb[ks & 1][t] = Vg[base + ((ks + 2) * 32 + g * 8 + (t & 7)) * E_ + vcol + (t >> 3) * 16];
        }
        #pragma unroll
        for (int mt = 0; mt < 8; ++mt) {
            const int q = mt * 16 + cl;        // P row; q&15 == cl
            const bf16x8 pa = *(const bf16x8*)&Sm[q * BS_ + (((ks * 4 + g) ^ cl) * 8)];
            acc2[mt][0] = __builtin_amdgcn_mfma_f32_16x16x32_bf16(pa, bv0, acc2[mt][0], 0, 0, 0);
            acc2[mt][1] = __builtin_amdgcn_mfma_f32_16x16x32_bf16(pa, bv1, acc2[mt][1], 0, 0, 0);
        }
    }
    __builtin_amdgcn_s_setprio(0);

    #pragma unroll
    for (int mt = 0; mt < 8; ++mt)
        #pragma unroll
        for (int n2 = 0; n2 < 2; ++n2)
            #pragma unroll
            for (int r = 0; r < 4; ++r)
                __builtin_nontemporal_store(acc2[mt][n2][r],
                    Og + base + (mt * 16 + g * 4 + r) * E_ + vcol + n2 * 16);
}

extern "C" void kernel_launch(void* const* d_in, const int* in_sizes, int n_in,
                              void* d_out, int out_size, void* d_ws, size_t ws_size,
                              hipStream_t stream) {
    const float* Q = (const float*)d_in[0];
    const float* K = (const float*)d_in[1];
    const float* V = (const float*)d_in[2];
    float* O = (float*)d_out;
    const int b = in_sizes[0] / (T_ * E_);            // 16
    float* A = O + (size_t)b * T_ * E_;               // output #2 region of d_out
    dim3 grid(b * (T_ / BS_));                        // 1024 tiles
    dim3 block(512);
    dba_fused<<<grid, block, 0, stream>>>(Q, K, V, A, O);
}

// Round 4
// 448.752 us; speedup vs baseline: 1.0609x; 1.0561x over previous
//
#include <hip/hip_runtime.h>

#define T_  8192
#define E_  256
#define BS_ 128

typedef __attribute__((ext_vector_type(8))) short bf16x8;
typedef __attribute__((ext_vector_type(4))) float f32x4;
typedef __attribute__((ext_vector_type(4))) unsigned int u32x4;

// Pair-convert via native __bf16 casts: compiler emits v_cvt_pk_bf16_f32 (RTNE).
// Round-3 cycle analysis: absolute VALU time unchanged vs bit-math, so this is
// safe to keep (and saves static instructions).
__device__ __forceinline__ unsigned pkbf(float a, float b) {
    unsigned short ua = __builtin_bit_cast(unsigned short, (__bf16)a);
    unsigned short ub = __builtin_bit_cast(unsigned short, (__bf16)b);
    return (unsigned)ua | ((unsigned)ub << 16);
}

__device__ __forceinline__ unsigned short bf1(float a) {
    return __builtin_bit_cast(unsigned short, (__bf16)a);
}

__device__ __forceinline__ bf16x8 pack8(f32x4 a, f32x4 b) {
    u32x4 u;
    u[0] = pkbf(a[0], a[1]); u[1] = pkbf(a[2], a[3]);
    u[2] = pkbf(b[0], b[1]); u[3] = pkbf(b[2], b[3]);
    return __builtin_bit_cast(bf16x8, u);
}

// Raw barrier: orders LDS only (lgkmcnt(0) + s_barrier). Global loads/stores
// stay in flight across it.
__device__ __forceinline__ void lds_barrier() {
    asm volatile("s_waitcnt lgkmcnt(0)" ::: "memory");
    __builtin_amdgcn_s_barrier();
}

// Fused diag-block attention, one WG per (batch,block) tile, 512 thr = 8 waves.
// Round-1 structure: rolling Q prefetch depth-1, V depth-2 prefetch issued
// right after QK^T, P bounced through LDS (reuses K buffer), A fp32
// fire-and-forget NT stores, raw lgkm-only barriers, V read straight from
// global in PV (each byte once per WG).
// MEASURED LESSONS (do not re-try):
//  - r2: preloading all 8 Q k-steps (qf[16]) spills past the 128-VGPR budget
//    (+18 MB scratch writes, +55% time).
//  - r2/r3: removing __builtin_nontemporal_load from the streaming Q/K/V
//    loads costs +65 us/dispatch at IDENTICAL traffic (3.67->2.42 TB/s
//    effective) — the NT evict-first hint is load-bearing for latency
//    hiding. Keep NT on ALL global loads.
//  - r3: s_setprio around MFMA phases: neutral here (barrier-locked phases).
__global__ __launch_bounds__(512, 4) void dba_fused(
        const float* __restrict__ Qg, const float* __restrict__ Kg,
        const float* __restrict__ Vg, float* __restrict__ Ag,
        float* __restrict__ Og)
{
    __shared__ unsigned short Sm[BS_ * E_];   // 64 KB: K[128][256] bf16; later P[128][128] bf16 in low 32 KB

    const int tid  = threadIdx.x;
    const int lane = tid & 63;
    const int w    = tid >> 6;     // wave 0..7
    const int cl   = lane & 15;    // col (C layout) / m (A layout) / n (B layout)
    const int g    = lane >> 4;    // quad group 0..3
    const int bi   = blockIdx.x >> 6;
    const int ni   = blockIdx.x & 63;
    const int base  = (bi * T_ + ni * BS_) * E_;
    const int abase = (bi * T_ + ni * BS_) * BS_;
    const int vcol  = w * 32 + cl;             // this wave's O/V column base

    // Q fragment for ks=0, issued before K staging (raw barrier won't drain it)
    const float* qp = Qg + base + (w * 16 + cl) * E_;
    f32x4 q0 = __builtin_nontemporal_load((const f32x4*)(qp + g * 8));
    f32x4 q1 = __builtin_nontemporal_load((const f32x4*)(qp + g * 8 + 4));

    // ---- stage K: fp32 global -> bf16 LDS, 16B-chunk XOR swizzle by (row&15) ----
    {
        const int c4   = lane * 4;            // col 0..252 step 4
        const int chnk = c4 >> 3;
        const int klow = c4 & 7;              // 0 or 4
        #pragma unroll 8
        for (int i = 0; i < 16; ++i) {
            const int n = i * 8 + w;          // key row 0..127
            f32x4 kv = __builtin_nontemporal_load((const f32x4*)(Kg + base + n * E_ + c4));
            const int cp = chnk ^ (n & 15);
            uint2 pk;
            pk.x = pkbf(kv[0], kv[1]);
            pk.y = pkbf(kv[2], kv[3]);
            *(uint2*)&Sm[n * E_ + cp * 8 + klow] = pk;
        }
    }
    lds_barrier();

    // ---- S = Q K^T via mfma_f32_16x16x32_bf16; wave w: 1 row-tile x 8 col-tiles ----
    f32x4 acc[8];
    #pragma unroll
    for (int nt = 0; nt < 8; ++nt) acc[nt] = (f32x4){0.f, 0.f, 0.f, 0.f};

    for (int ks = 0; ks < 8; ++ks) {          // contraction: 8 steps of 32
        bf16x8 aq = pack8(q0, q1);
        if (ks < 7) {
            const int kn = (ks + 1) * 32 + g * 8;
            q0 = __builtin_nontemporal_load((const f32x4*)(qp + kn));
            q1 = __builtin_nontemporal_load((const f32x4*)(qp + kn + 4));
        }
        #pragma unroll
        for (int nt = 0; nt < 8; ++nt) {
            const int n  = nt * 16 + cl;      // key row
            const int cp = (ks * 4 + g) ^ cl;
            bf16x8 bk = *(const bf16x8*)&Sm[n * E_ + cp * 8];
            acc[nt] = __builtin_amdgcn_mfma_f32_16x16x32_bf16(aq, bk, acc[nt], 0, 0, 0);
        }
    }

    // ---- prefetch V k-steps 0,1 (32 coalesced dwords): HBM latency hides under
    //      softmax + A-store + P-LDS write + two barriers ----
    float vb[2][16];
    #pragma unroll
    for (int t = 0; t < 16; ++t)
        vb[0][t] = __builtin_nontemporal_load(
            Vg + base + (g * 8 + (t & 7)) * E_ + vcol + (t >> 3) * 16);
    #pragma unroll
    for (int t = 0; t < 16; ++t)
        vb[1][t] = __builtin_nontemporal_load(
            Vg + base + (32 + g * 8 + (t & 7)) * E_ + vcol + (t >> 3) * 16);

    // ---- mask + softmax. C layout: col = 16*nt + cl, row = 16*w + 4*g + r ----
    const float scale = 0.0625f;               // 1/sqrt(256)
    const float L2E   = 1.4426950408889634f;
    #pragma unroll
    for (int r = 0; r < 4; ++r) {
        const int q = w * 16 + g * 4 + r;      // local query row
        float m = -__builtin_inff();
        #pragma unroll
        for (int nt = 0; nt < 8; ++nt) {
            const int c = nt * 16 + cl;
            float z = acc[nt][r] * scale;
            z = (c > q) ? -__builtin_inff() : z;
            acc[nt][r] = z;
            m = fmaxf(m, z);
        }
        m = fmaxf(m, __shfl_xor(m, 1));
        m = fmaxf(m, __shfl_xor(m, 2));
        m = fmaxf(m, __shfl_xor(m, 4));
        m = fmaxf(m, __shfl_xor(m, 8));
        float s = 0.f;
        #pragma unroll
        for (int nt = 0; nt < 8; ++nt) {
            const float p = exp2f((acc[nt][r] - m) * L2E);
            acc[nt][r] = p;
            s += p;
        }
        s += __shfl_xor(s, 1);
        s += __shfl_xor(s, 2);
        s += __shfl_xor(s, 4);
        s += __shfl_xor(s, 8);
        const float rinv = __builtin_amdgcn_rcpf(s);
        #pragma unroll
        for (int nt = 0; nt < 8; ++nt)
            acc[nt][r] *= rinv;
    }

    // ---- store A (fp32, mandatory output #2). Fire-and-forget. ----
    #pragma unroll
    for (int nt = 0; nt < 8; ++nt)
        #pragma unroll
        for (int r = 0; r < 4; ++r)
            __builtin_nontemporal_store(acc[nt][r],
                Ag + abase + (w * 16 + g * 4 + r) * BS_ + nt * 16 + cl);

    lds_barrier();   // all waves done reading K-LDS; safe to overwrite with P

    // ---- P (bf16) -> LDS [q][k], same 16B-chunk XOR swizzle by (q&15) ----
    #pragma unroll
    for (int nt = 0; nt < 8; ++nt)
        #pragma unroll
        for (int r = 0; r < 4; ++r) {
            const int q = w * 16 + g * 4 + r;
            const int k = nt * 16 + cl;
            Sm[q * BS_ + (((k >> 3) ^ (g * 4 + r)) * 8) + (k & 7)] = bf1(acc[nt][r]);
        }

    lds_barrier();   // P visible WG-wide

    // ---- O = P V: wave w owns output cols [32w,32w+32), all 8 q-row tiles.
    //      A-operand from P-LDS (swizzled b128 reads), B-operand = V from
    //      global (each byte read exactly once per WG), depth-2 prefetch. ----
    f32x4 acc2[8][2];
    #pragma unroll
    for (int mt = 0; mt < 8; ++mt) {
        acc2[mt][0] = (f32x4){0.f, 0.f, 0.f, 0.f};
        acc2[mt][1] = (f32x4){0.f, 0.f, 0.f, 0.f};
    }

    #pragma unroll
    for (int ks = 0; ks < 4; ++ks) {
        f32x4 v0a = {vb[ks & 1][0],  vb[ks & 1][1],  vb[ks & 1][2],  vb[ks & 1][3]};
        f32x4 v0b = {vb[ks & 1][4],  vb[ks & 1][5],  vb[ks & 1][6],  vb[ks & 1][7]};
        f32x4 v1a = {vb[ks & 1][8],  vb[ks & 1][9],  vb[ks & 1][10], vb[ks & 1][11]};
        f32x4 v1b = {vb[ks & 1][12], vb[ks & 1][13], vb[ks & 1][14], vb[ks & 1][15]};
        bf16x8 bv0 = pack8(v0a, v0b);
        bf16x8 bv1 = pack8(v1a, v1b);
        if (ks < 2) {   // prefetch k-steps 2,3 into the buffer just consumed
            #pragma unroll
            for (int t = 0; t < 16; ++t)
                vb[ks & 1][t] = __builtin_nontemporal_load(
                    Vg + base + ((ks + 2) * 32 + g * 8 + (t & 7)) * E_ + vcol + (t >> 3) * 16);
        }
        #pragma unroll
        for (int mt = 0; mt < 8; ++mt) {
            const int q = mt * 16 + cl;        // P row; q&15 == cl
            const bf16x8 pa = *(const bf16x8*)&Sm[q * BS_ + (((ks * 4 + g) ^ cl) * 8)];
            acc2[mt][0] = __builtin_amdgcn_mfma_f32_16x16x32_bf16(pa, bv0, acc2[mt][0], 0, 0, 0);
            acc2[mt][1] = __builtin_amdgcn_mfma_f32_16x16x32_bf16(pa, bv1, acc2[mt][1], 0, 0, 0);
        }
    }

    #pragma unroll
    for (int mt = 0; mt < 8; ++mt)
        #pragma unroll
        for (int n2 = 0; n2 < 2; ++n2)
            #pragma unroll
            for (int r = 0; r < 4; ++r)
                __builtin_nontemporal_store(acc2[mt][n2][r],
                    Og + base + (mt * 16 + g * 4 + r) * E_ + vcol + n2 * 16);
}

extern "C" void kernel_launch(void* const* d_in, const int* in_sizes, int n_in,
                              void* d_out, int out_size, void* d_ws, size_t ws_size,
                              hipStream_t stream) {
    const float* Q = (const float*)d_in[0];
    const float* K = (const float*)d_in[1];
    const float* V = (const float*)d_in[2];
    float* O = (float*)d_out;
    const int b = in_sizes[0] / (T_ * E_);            // 16
    float* A = O + (size_t)b * T_ * E_;               // output #2 region of d_out
    dim3 grid(b * (T_ / BS_));                        // 1024 tiles
    dim3 block(512);
    dba_fused<<<grid, block, 0, stream>>>(Q, K, V, A, O);
}